// Round 11
// baseline (127.882 us; speedup 1.0000x reference)
//
#include <hip/hip_runtime.h>
#include <stdint.h>
#include <stddef.h>

typedef int v4i __attribute__((ext_vector_type(4)));

#define GLOAD_LDS16(g, l) __builtin_amdgcn_global_load_lds( \
    (const __attribute__((address_space(1))) void*)(g),     \
    (__attribute__((address_space(3))) void*)(l), 16, 0, 0)

// ---------------------------------------------------------------------------
// Quantize x rows (length 2048): one wave per row, 4 rows per block.
// scale = max(amax/127, floorv); q = clip(rint(v/scale), -128, 127)
// ---------------------------------------------------------------------------
__device__ __forceinline__ int pack4(float4 f, float s) {
    int a = (int)rintf(f.x / s); a = a < -128 ? -128 : (a > 127 ? 127 : a);
    int b = (int)rintf(f.y / s); b = b < -128 ? -128 : (b > 127 ? 127 : b);
    int c = (int)rintf(f.z / s); c = c < -128 ? -128 : (c > 127 ? 127 : c);
    int d = (int)rintf(f.w / s); d = d < -128 ? -128 : (d > 127 ? 127 : d);
    return (a & 255) | ((b & 255) << 8) | ((c & 255) << 16) | ((d & 255) << 24);
}

__global__ __launch_bounds__(256) void quant_rows_2048(
    const float* __restrict__ in, signed char* __restrict__ q,
    float* __restrict__ scales, float floorv)
{
    const int lane = threadIdx.x & 63;
    const int row  = blockIdx.x * 4 + (threadIdx.x >> 6);
    const float* rp = in + (size_t)row * 2048;

    float4 v[8];
#pragma unroll
    for (int j = 0; j < 2; ++j) {
        const float4* p = (const float4*)(rp + j * 1024 + lane * 16);
#pragma unroll
        for (int i = 0; i < 4; ++i) v[j * 4 + i] = p[i];
    }
    float am = 0.0f;
#pragma unroll
    for (int i = 0; i < 8; ++i) {
        am = fmaxf(am, fabsf(v[i].x));
        am = fmaxf(am, fabsf(v[i].y));
        am = fmaxf(am, fabsf(v[i].z));
        am = fmaxf(am, fabsf(v[i].w));
    }
#pragma unroll
    for (int off = 32; off; off >>= 1) am = fmaxf(am, __shfl_xor(am, off));
    const float s = fmaxf(am / 127.0f, floorv);

#pragma unroll
    for (int j = 0; j < 2; ++j) {
        int4 pk;
        pk.x = pack4(v[j * 4 + 0], s);
        pk.y = pack4(v[j * 4 + 1], s);
        pk.z = pack4(v[j * 4 + 2], s);
        pk.w = pack4(v[j * 4 + 3], s);
        *(int4*)(q + (size_t)row * 2048 + j * 1024 + lane * 16) = pk;
    }
    if (lane == 0) scales[row] = s;
}

// ---------------------------------------------------------------------------
// Quantize w rows AND store in MFMA-fragment-native transposed layout:
// wq_t is organized as 1KB frag-blocks indexed (f = col/16, t = ktile):
//   block (f,t) byte l*16.. holds wq[f*16 + (l&15)][t*64 + (l>>4)*16 .. +16]
// so the GEMM's B-frag load is ONE fully coalesced global_load_dwordx4/wave.
// Store from quant: row r = f*16+rl; 16B chunk kb = j*64+lane covers
// k-bytes kb*16..; t = kb>>2, sub = kb&3; dest = (f*32+t)*1024 + rl*16 + sub*256.
// ---------------------------------------------------------------------------
__global__ __launch_bounds__(256) void quant_w_t(
    const float* __restrict__ in, signed char* __restrict__ qt,
    float* __restrict__ scales)
{
    const int lane = threadIdx.x & 63;
    const int row  = blockIdx.x * 4 + (threadIdx.x >> 6);
    const int f    = row >> 4;
    const int rl   = row & 15;
    const float* rp = in + (size_t)row * 2048;

    float4 v[8];
#pragma unroll
    for (int j = 0; j < 2; ++j) {
        const float4* p = (const float4*)(rp + j * 1024 + lane * 16);
#pragma unroll
        for (int i = 0; i < 4; ++i) v[j * 4 + i] = p[i];
    }
    float am = 0.0f;
#pragma unroll
    for (int i = 0; i < 8; ++i) {
        am = fmaxf(am, fabsf(v[i].x));
        am = fmaxf(am, fabsf(v[i].y));
        am = fmaxf(am, fabsf(v[i].z));
        am = fmaxf(am, fabsf(v[i].w));
    }
#pragma unroll
    for (int off = 32; off; off >>= 1) am = fmaxf(am, __shfl_xor(am, off));
    const float s = fmaxf(am / 127.0f, 1e-8f / 127.0f);

#pragma unroll
    for (int j = 0; j < 2; ++j) {
        int4 pk;
        pk.x = pack4(v[j * 4 + 0], s);
        pk.y = pack4(v[j * 4 + 1], s);
        pk.z = pack4(v[j * 4 + 2], s);
        pk.w = pack4(v[j * 4 + 3], s);
        const int kb  = j * 64 + lane;      // 16B-chunk index 0..127
        const int t   = kb >> 2;            // ktile 0..31
        const int sub = kb & 3;             // k-quarter within tile
        *(int4*)(qt + (((size_t)(f * 32 + t)) << 10) + (rl << 4) + (sub << 8)) = pk;
    }
    if (lane == 0) scales[row] = s;
}

// ---------------------------------------------------------------------------
// int8 GEMM — A-only LDS ring + frag-native B from global (R9 sync skeleton):
// 128x256 tile, BK=64, 512 thr = 8 waves (2M x 4N), wave 64x64 via 4x4 frags
// of mfma_i32_16x16x64_i8. A: LDS ring-3 (3 x 8KB = 24KB), 1 gload_lds/thread
// per tile, chunk-XOR swizzle. B: 4 coalesced 1KB global_load_dwordx4 per
// wave per tile from wq_t (L2-resident, 4MB), double-buffered bc/bn in regs.
// Per tile t: {4 B-loads(t+1) FIRST; 1 A-gload(t+2); 4 ds_read A; 16 MFMA;
//   vmcnt(1)+lgkmcnt(0) (drains A(t+1)+B(t+1), leaves A(t+2) in flight —
//   counted, never 0 mid-loop); raw s_barrier}. Tail: vmcnt(0) at t=NT-2.
// WAR-safe: lgkmcnt(0) pre-barrier => all reads of buf (t-1)%3 returned
// before any wave issues the A(t+2) overwrite of that buf after the barrier.
// Window floor: MFMA 1306 cyc/SIMD > LDS ~900 > L2-B ~585 — MFMA-bound.
// ---------------------------------------------------------------------------
__global__ __launch_bounds__(512, 4) void gemm_i8_bt(
    const signed char* __restrict__ xq, const signed char* __restrict__ wqt,
    const float* __restrict__ xs, const float* __restrict__ ws,
    const float* __restrict__ bias, float* __restrict__ out, int K)
{
    __shared__ __align__(16) signed char lds[24576]; // 3 x A[8192]

    const int tid  = threadIdx.x;
    const int lane = tid & 63;
    const int wid  = tid >> 6;
    const int wm   = wid >> 2;        // 0..1
    const int wn   = wid & 3;         // 0..3

    const int nwg  = gridDim.x * gridDim.y;
    int orig = blockIdx.y * gridDim.x + blockIdx.x;
    int swz  = ((nwg & 7) == 0) ? ((orig & 7) * (nwg >> 3) + (orig >> 3)) : orig;
    const int brow = (swz / gridDim.x) * 128;
    const int bcol = (swz % gridDim.x) * 256;

    // A staging: thread -> (row = tid>>2, chunk = tid&3), swizzled source
    const int gch  = (((tid & 3) ^ ((tid >> 3) & 3)) << 4);
    const int lofs = tid << 4;
    const signed char* gA = xq + (size_t)(brow + (tid >> 2)) * K;

#define BUFOFF(bb) ((bb) * 8192)
#define ST_A(tt, bb) GLOAD_LDS16(gA + (size_t)(tt) * 64 + gch, \
                                 lds + BUFOFF(bb) + lofs)

    const int rl   = lane & 15;
    const int ko   = lane >> 4;
    const int slot = ((ko ^ ((rl >> 1) & 3)) << 4);

#define FRAG_A(bb, r) (*(const v4i*)(lds + BUFOFF(bb) + (r) * 64 + slot))

    // B: frag-native; frag n of this wave lives at block (f0+n, t)
    const int NTc = K >> 6;
    const signed char* gB = wqt + (((size_t)((bcol >> 4) + wn * 4) * NTc) << 10) + (lane << 4);
    const size_t bns = ((size_t)NTc) << 10;   // stride between frag n blocks

    v4i acc[4][4] = {};
    const int ar = wm * 64 + rl;

    // ---- prologue: A(0), then B(0) x4, then A(1); vmcnt(1) leaves A(1)
    ST_A(0, 0);
    v4i bc0 = *(const v4i*)(gB);
    v4i bc1 = *(const v4i*)(gB + bns);
    v4i bc2 = *(const v4i*)(gB + 2 * bns);
    v4i bc3 = *(const v4i*)(gB + 3 * bns);
    ST_A(1, 1);
    asm volatile("s_waitcnt vmcnt(1)" ::: "memory");
    __builtin_amdgcn_s_barrier();

    const int NT = NTc;   // 32
    for (int t = 0; t < NT; ++t) {
        const int buf = t % 3;
        v4i bn0, bn1, bn2, bn3;
        if (t + 1 < NT) {
            const signed char* gBt = gB + ((size_t)(t + 1) << 10);
            bn0 = *(const v4i*)(gBt);
            bn1 = *(const v4i*)(gBt + bns);
            bn2 = *(const v4i*)(gBt + 2 * bns);
            bn3 = *(const v4i*)(gBt + 3 * bns);
        }
        if (t + 2 < NT) ST_A(t + 2, (t + 2) % 3);

        v4i af[4];
#pragma unroll
        for (int m = 0; m < 4; ++m) af[m] = FRAG_A(buf, ar + m * 16);
        __builtin_amdgcn_s_setprio(1);
#pragma unroll
        for (int m = 0; m < 4; ++m) {
            acc[m][0] = __builtin_amdgcn_mfma_i32_16x16x64_i8(af[m], bc0, acc[m][0], 0, 0, 0);
            acc[m][1] = __builtin_amdgcn_mfma_i32_16x16x64_i8(af[m], bc1, acc[m][1], 0, 0, 0);
            acc[m][2] = __builtin_amdgcn_mfma_i32_16x16x64_i8(af[m], bc2, acc[m][2], 0, 0, 0);
            acc[m][3] = __builtin_amdgcn_mfma_i32_16x16x64_i8(af[m], bc3, acc[m][3], 0, 0, 0);
        }
        __builtin_amdgcn_s_setprio(0);

        if (t + 2 < NT) {
            // drain A(t+1) + B(t+1); keep only A(t+2) in flight
            asm volatile("s_waitcnt vmcnt(1) lgkmcnt(0)" ::: "memory");
            __builtin_amdgcn_s_barrier();
        } else if (t + 1 < NT) {
            // t == NT-2: drain B(NT-1) (all A already staged)
            asm volatile("s_waitcnt vmcnt(0) lgkmcnt(0)" ::: "memory");
            __builtin_amdgcn_s_barrier();
        }
        bc0 = bn0; bc1 = bn1; bc2 = bn2; bc3 = bn3;
    }

    // ---- epilogue: C/D layout col = lane&15, row = (lane>>4)*4 + j
    const int rg = lane >> 4;
#pragma unroll
    for (int n = 0; n < 4; ++n) {
        const int col = bcol + wn * 64 + n * 16 + rl;
        const float wsc = ws[col];
        const float bv  = bias[col];
#pragma unroll
        for (int m = 0; m < 4; ++m) {
#pragma unroll
            for (int j = 0; j < 4; ++j) {
                const int row = brow + wm * 64 + m * 16 + rg * 4 + j;
                out[(size_t)row * 2048 + col] =
                    (float)acc[m][n][j] * xs[row] * wsc + bv;
            }
        }
    }
#undef ST_A
#undef BUFOFF
#undef FRAG_A
}

// ---------------------------------------------------------------------------
extern "C" void kernel_launch(void* const* d_in, const int* in_sizes, int n_in,
                              void* d_out, int out_size, void* d_ws, size_t ws_size,
                              hipStream_t stream) {
    const float* x    = (const float*)d_in[0];   // [B,N,D] = [4,4096,2048]
    const float* w    = (const float*)d_in[1];   // [O,D]   = [2048,2048]
    const float* bias = (const float*)d_in[2];   // [O]
    float* out = (float*)d_out;

    const int D = 2048;
    const int O = in_sizes[2];                   // 2048
    const int M = in_sizes[0] / D;               // 16384

    char* wsb = (char*)d_ws;
    signed char* xq  = (signed char*)wsb;
    signed char* wqt = (signed char*)(wsb + (size_t)M * D);
    float* xs  = (float*)(wsb + (size_t)M * D + (size_t)O * D);
    float* wsc = (float*)(wsb + (size_t)M * D + (size_t)O * D + (size_t)M * 4);

    quant_rows_2048<<<M / 4, 256, 0, stream>>>(x, xq, xs, 1e-12f);
    quant_w_t<<<O / 4, 256, 0, stream>>>(w, wqt, wsc);

    dim3 grid(O / 256, M / 128);   // (8, 128) = 1024 blocks, %8 == 0
    gemm_i8_bt<<<grid, 512, 0, stream>>>(xq, wqt, xs, wsc, bias, out, D);
}

// Round 12
// 124.488 us; speedup vs baseline: 1.0273x; 1.0273x over previous
//
#include <hip/hip_runtime.h>
#include <stdint.h>
#include <stddef.h>

typedef int v4i __attribute__((ext_vector_type(4)));

#define GLOAD_LDS16(g, l) __builtin_amdgcn_global_load_lds( \
    (const __attribute__((address_space(1))) void*)(g),     \
    (__attribute__((address_space(3))) void*)(l), 16, 0, 0)

// ---------------------------------------------------------------------------
// Quantize x rows (length 2048): one wave per row, 4 rows per block.
// scale = max(amax/127, floorv); q = clip(rint(v/scale), -128, 127)
// ---------------------------------------------------------------------------
__device__ __forceinline__ int pack4(float4 f, float s) {
    int a = (int)rintf(f.x / s); a = a < -128 ? -128 : (a > 127 ? 127 : a);
    int b = (int)rintf(f.y / s); b = b < -128 ? -128 : (b > 127 ? 127 : b);
    int c = (int)rintf(f.z / s); c = c < -128 ? -128 : (c > 127 ? 127 : c);
    int d = (int)rintf(f.w / s); d = d < -128 ? -128 : (d > 127 ? 127 : d);
    return (a & 255) | ((b & 255) << 8) | ((c & 255) << 16) | ((d & 255) << 24);
}

__global__ __launch_bounds__(256) void quant_rows_2048(
    const float* __restrict__ in, signed char* __restrict__ q,
    float* __restrict__ scales, float floorv)
{
    const int lane = threadIdx.x & 63;
    const int row  = blockIdx.x * 4 + (threadIdx.x >> 6);
    const float* rp = in + (size_t)row * 2048;

    float4 v[8];
#pragma unroll
    for (int j = 0; j < 2; ++j) {
        const float4* p = (const float4*)(rp + j * 1024 + lane * 16);
#pragma unroll
        for (int i = 0; i < 4; ++i) v[j * 4 + i] = p[i];
    }
    float am = 0.0f;
#pragma unroll
    for (int i = 0; i < 8; ++i) {
        am = fmaxf(am, fabsf(v[i].x));
        am = fmaxf(am, fabsf(v[i].y));
        am = fmaxf(am, fabsf(v[i].z));
        am = fmaxf(am, fabsf(v[i].w));
    }
#pragma unroll
    for (int off = 32; off; off >>= 1) am = fmaxf(am, __shfl_xor(am, off));
    const float s = fmaxf(am / 127.0f, floorv);

#pragma unroll
    for (int j = 0; j < 2; ++j) {
        int4 pk;
        pk.x = pack4(v[j * 4 + 0], s);
        pk.y = pack4(v[j * 4 + 1], s);
        pk.z = pack4(v[j * 4 + 2], s);
        pk.w = pack4(v[j * 4 + 3], s);
        *(int4*)(q + (size_t)row * 2048 + j * 1024 + lane * 16) = pk;
    }
    if (lane == 0) scales[row] = s;
}

// ---------------------------------------------------------------------------
// Quantize w rows AND store MFMA-fragment-native: 1KB blocks (f=col/16, t64):
// block byte l*16.. = wq[f*16 + (l&15)][t64*64 + (l>>4)*16 .. +16]  — one
// coalesced global_load_dwordx4 per wave = one B fragment. (Verified R11.)
// ---------------------------------------------------------------------------
__global__ __launch_bounds__(256) void quant_w_t(
    const float* __restrict__ in, signed char* __restrict__ qt,
    float* __restrict__ scales)
{
    const int lane = threadIdx.x & 63;
    const int row  = blockIdx.x * 4 + (threadIdx.x >> 6);
    const int f    = row >> 4;
    const int rl   = row & 15;
    const float* rp = in + (size_t)row * 2048;

    float4 v[8];
#pragma unroll
    for (int j = 0; j < 2; ++j) {
        const float4* p = (const float4*)(rp + j * 1024 + lane * 16);
#pragma unroll
        for (int i = 0; i < 4; ++i) v[j * 4 + i] = p[i];
    }
    float am = 0.0f;
#pragma unroll
    for (int i = 0; i < 8; ++i) {
        am = fmaxf(am, fabsf(v[i].x));
        am = fmaxf(am, fabsf(v[i].y));
        am = fmaxf(am, fabsf(v[i].z));
        am = fmaxf(am, fabsf(v[i].w));
    }
#pragma unroll
    for (int off = 32; off; off >>= 1) am = fmaxf(am, __shfl_xor(am, off));
    const float s = fmaxf(am / 127.0f, 1e-8f / 127.0f);

#pragma unroll
    for (int j = 0; j < 2; ++j) {
        int4 pk;
        pk.x = pack4(v[j * 4 + 0], s);
        pk.y = pack4(v[j * 4 + 1], s);
        pk.z = pack4(v[j * 4 + 2], s);
        pk.w = pack4(v[j * 4 + 3], s);
        const int kb  = j * 64 + lane;      // 16B-chunk index 0..127
        const int t   = kb >> 2;            // t64 0..31
        const int sub = kb & 3;             // k-quarter within 64
        *(int4*)(qt + (((size_t)(f * 32 + t)) << 10) + (rl << 4) + (sub << 8)) = pk;
    }
    if (lane == 0) scales[row] = s;
}

// ---------------------------------------------------------------------------
// int8 GEMM — BK=128 (2x work per sync), A-only LDS ring-3, frag-native B.
// 128x128 block-tile, 256 thr = 4 waves (2M x 2N), wave 64x64 via 4x4 frags
// of mfma_i32_16x16x64_i8; 32 MFMA/wave/tile, NT=16 (half the barriers of
// BK=64). A: LDS ring-3 x 16KB = 48KB -> 3 blocks/CU; B: 8 coalesced 1KB
// frag loads/tile from wq_t (register waits by compiler). Per tile:
//  {8 ds_read (ks0+ks1); 8 B loads; 4 ST_A(t+2); vmcnt(8) lgkm(4) ->
//   16 MFMA ks0; vmcnt(4) lgkm(0) -> 16 MFMA ks1; s_barrier}.
// vmcnt(8) drains the 4 OLDEST ops = ST_A(t+1) (residency guarantee,
// order-robust); vmcnt never 0 mid-loop. WAR: all ds_reads returned at
// lgkm(0) before the barrier; overwrite of buf (t-1)%3 is issued after it.
// Swizzle: LDS chunk c of row r holds global chunk c^(r&7); read chunk
// (q ^ (rl&7)) — 2 lanes/chunk per 16-lane group = free (m136).
// ---------------------------------------------------------------------------
__global__ __launch_bounds__(256, 3) void gemm_i8_bk128(
    const signed char* __restrict__ xq, const signed char* __restrict__ wqt,
    const float* __restrict__ xs, const float* __restrict__ ws,
    const float* __restrict__ bias, float* __restrict__ out, int K)
{
    __shared__ __align__(16) signed char lds[49152]; // 3 x A[16384]

    const int tid  = threadIdx.x;
    const int lane = tid & 63;
    const int wid  = tid >> 6;        // 0..3
    const int wm   = wid >> 1;        // 0..1
    const int wn   = wid & 1;         // 0..1

    const int nwg  = gridDim.x * gridDim.y;
    int orig = blockIdx.y * gridDim.x + blockIdx.x;
    int swz  = ((nwg & 7) == 0) ? ((orig & 7) * (nwg >> 3) + (orig >> 3)) : orig;
    const int brow = (swz / gridDim.x) * 128;
    const int bcol = (swz % gridDim.x) * 128;

    // A staging: thread -> (row = s*32 + (tid>>3), chunk = tid&7), swz source
    const int gch = (((tid & 7) ^ ((tid >> 3) & 7)) << 4);
    const signed char* gA = xq + (size_t)(brow + (tid >> 3)) * K;

#define ST_A4(tt, bb) do {                                                                    \
    GLOAD_LDS16(gA + (size_t)(tt) * 128 + gch,                      lds + (bb) * 16384 + (tid << 4));          \
    GLOAD_LDS16(gA + (size_t)(32) * K + (size_t)(tt) * 128 + gch,   lds + (bb) * 16384 + 4096 + (tid << 4));   \
    GLOAD_LDS16(gA + (size_t)(64) * K + (size_t)(tt) * 128 + gch,   lds + (bb) * 16384 + 8192 + (tid << 4));   \
    GLOAD_LDS16(gA + (size_t)(96) * K + (size_t)(tt) * 128 + gch,   lds + (bb) * 16384 + 12288 + (tid << 4));  \
} while (0)

    const int rl = lane & 15;
    const int ko = lane >> 4;
    const int c0 = ((ko ^ (rl & 7)) << 4);         // ks0 chunk byte
    const int c1 = (((4 + ko) ^ (rl & 7)) << 4);   // ks1 chunk byte

#define FRAG_A(bb, r, cc) (*(const v4i*)(lds + (bb) * 16384 + (r) * 128 + (cc)))

    // B: frag-native; wave covers frags f0..f0+3; per tile 2 k-slices
    const int NT64 = K >> 6;   // 32
    const signed char* gB = wqt + (((size_t)((bcol >> 4) + wn * 4) * NT64) << 10) + (lane << 4);
    const size_t bns = ((size_t)NT64) << 10;

    v4i acc[4][4] = {};
    const int ar = wm * 64 + rl;

    // ---- prologue: stage A(0), A(1); counted wait; barrier
    ST_A4(0, 0);
    ST_A4(1, 1);
    asm volatile("s_waitcnt vmcnt(4)" ::: "memory");
    __builtin_amdgcn_s_barrier();

    const int NT = K >> 7;   // 16
    for (int t = 0; t < NT; ++t) {
        const int buf = t % 3;
        const bool st2 = (t + 2 < NT);

        // B loads: ks0 then ks1 (8 VMEM)
        const signed char* gBt = gB + (((size_t)(2 * t)) << 10);
        v4i bc0 = *(const v4i*)(gBt);
        v4i bc1 = *(const v4i*)(gBt + bns);
        v4i bc2 = *(const v4i*)(gBt + 2 * bns);
        v4i bc3 = *(const v4i*)(gBt + 3 * bns);
        v4i bn0 = *(const v4i*)(gBt + 1024);
        v4i bn1 = *(const v4i*)(gBt + bns + 1024);
        v4i bn2 = *(const v4i*)(gBt + 2 * bns + 1024);
        v4i bn3 = *(const v4i*)(gBt + 3 * bns + 1024);
        if (st2) ST_A4(t + 2, (t + 2) % 3);

        // ds reads: ks0 then ks1 (8 DS)
        v4i af0 = FRAG_A(buf, ar,      c0);
        v4i af1 = FRAG_A(buf, ar + 16, c0);
        v4i af2 = FRAG_A(buf, ar + 32, c0);
        v4i af3 = FRAG_A(buf, ar + 48, c0);
        v4i an0 = FRAG_A(buf, ar,      c1);
        v4i an1 = FRAG_A(buf, ar + 16, c1);
        v4i an2 = FRAG_A(buf, ar + 32, c1);
        v4i an3 = FRAG_A(buf, ar + 48, c1);

        if (st2) asm volatile("s_waitcnt vmcnt(8) lgkmcnt(4)" ::: "memory");
        else     asm volatile("s_waitcnt vmcnt(4) lgkmcnt(4)" ::: "memory");
        __builtin_amdgcn_sched_barrier(0);

        __builtin_amdgcn_s_setprio(1);
#pragma unroll
        for (int m = 0; m < 4; ++m) {
            v4i a = (m == 0) ? af0 : (m == 1) ? af1 : (m == 2) ? af2 : af3;
            acc[m][0] = __builtin_amdgcn_mfma_i32_16x16x64_i8(a, bc0, acc[m][0], 0, 0, 0);
            acc[m][1] = __builtin_amdgcn_mfma_i32_16x16x64_i8(a, bc1, acc[m][1], 0, 0, 0);
            acc[m][2] = __builtin_amdgcn_mfma_i32_16x16x64_i8(a, bc2, acc[m][2], 0, 0, 0);
            acc[m][3] = __builtin_amdgcn_mfma_i32_16x16x64_i8(a, bc3, acc[m][3], 0, 0, 0);
        }
        __builtin_amdgcn_s_setprio(0);

        if (st2) asm volatile("s_waitcnt vmcnt(4) lgkmcnt(0)" ::: "memory");
        else     asm volatile("s_waitcnt vmcnt(0) lgkmcnt(0)" ::: "memory");
        __builtin_amdgcn_sched_barrier(0);

        __builtin_amdgcn_s_setprio(1);
#pragma unroll
        for (int m = 0; m < 4; ++m) {
            v4i a = (m == 0) ? an0 : (m == 1) ? an1 : (m == 2) ? an2 : an3;
            acc[m][0] = __builtin_amdgcn_mfma_i32_16x16x64_i8(a, bn0, acc[m][0], 0, 0, 0);
            acc[m][1] = __builtin_amdgcn_mfma_i32_16x16x64_i8(a, bn1, acc[m][1], 0, 0, 0);
            acc[m][2] = __builtin_amdgcn_mfma_i32_16x16x64_i8(a, bn2, acc[m][2], 0, 0, 0);
            acc[m][3] = __builtin_amdgcn_mfma_i32_16x16x64_i8(a, bn3, acc[m][3], 0, 0, 0);
        }
        __builtin_amdgcn_s_setprio(0);

        __builtin_amdgcn_s_barrier();
    }

    // ---- epilogue: C/D layout col = lane&15, row = (lane>>4)*4 + j
    const int rg = lane >> 4;
#pragma unroll
    for (int n = 0; n < 4; ++n) {
        const int col = bcol + wn * 64 + n * 16 + rl;
        const float wsc = ws[col];
        const float bv  = bias[col];
#pragma unroll
        for (int m = 0; m < 4; ++m) {
#pragma unroll
            for (int j = 0; j < 4; ++j) {
                const int row = brow + wm * 64 + m * 16 + rg * 4 + j;
                out[(size_t)row * 2048 + col] =
                    (float)acc[m][n][j] * xs[row] * wsc + bv;
            }
        }
    }
#undef ST_A4
#undef FRAG_A
}

// ---------------------------------------------------------------------------
extern "C" void kernel_launch(void* const* d_in, const int* in_sizes, int n_in,
                              void* d_out, int out_size, void* d_ws, size_t ws_size,
                              hipStream_t stream) {
    const float* x    = (const float*)d_in[0];   // [B,N,D] = [4,4096,2048]
    const float* w    = (const float*)d_in[1];   // [O,D]   = [2048,2048]
    const float* bias = (const float*)d_in[2];   // [O]
    float* out = (float*)d_out;

    const int D = 2048;
    const int O = in_sizes[2];                   // 2048
    const int M = in_sizes[0] / D;               // 16384

    char* wsb = (char*)d_ws;
    signed char* xq  = (signed char*)wsb;
    signed char* wqt = (signed char*)(wsb + (size_t)M * D);
    float* xs  = (float*)(wsb + (size_t)M * D + (size_t)O * D);
    float* wsc = (float*)(wsb + (size_t)M * D + (size_t)O * D + (size_t)M * 4);

    quant_rows_2048<<<M / 4, 256, 0, stream>>>(x, xq, xs, 1e-12f);
    quant_w_t<<<O / 4, 256, 0, stream>>>(w, wqt, wsc);

    dim3 grid(O / 128, M / 128);   // (16, 128) = 2048 blocks, %8 == 0
    gemm_i8_bk128<<<grid, 256, 0, stream>>>(xq, wqt, xs, wsc, bias, out, D);
}